// Round 8
// baseline (188.705 us; speedup 1.0000x reference)
//
#include <hip/hip_runtime.h>
#include <cstdint>

#define GH 10
#define GW 10

// 64 samples per 256-thread block, three phases:
//  A: 4 lanes/sample dense float4 loads + pass-1 (float-abs math) -> LDS mask
//  B: lanes 0..63 flood ONE sample each (full 100-bit board in-lane, no
//     shuffles) + argmin + epilogue  -> LDS {cluster, K, gap_pen}
//  C: quads compute S_T from still-live registers, assemble loss.
// Rationale: flood cost per wave-iter is fixed; packing 64 boards/wave makes
// it 4x cheaper per sample than 16 boards/wave (round-7 bottleneck).
__global__ __launch_bounds__(256, 6) void custom_loss_kernel(
    const float* __restrict__ result,
    const int* __restrict__ points,
    float* __restrict__ out,
    int B)
{
    __shared__ uint64_t sMlo[64], sMhi[64];   // phase A -> B
    __shared__ uint64_t sClo[64], sChi[64];   // phase B -> C
    __shared__ float    sGapPen[64];
    __shared__ int      sK[64];
    __shared__ float    wsum[4];

    const int tix = threadIdx.x;
    const int s_local = tix >> 2;
    const int q = tix & 3;
    const int gs = blockIdx.x * 64 + s_local;
    const bool valid = (gs < B);

    // ===== phase A: dense quad loads + pass-1 =====
    float4 v4[7];
    float sum_all = 0.f, sc = 0.f, boxSum = 0.f, rs = 0.f, re = 0.f;
    int dy0i = 0, dx0i = 0;
    if (valid) {
        const float* __restrict__ r = result + (size_t)gs * 100;
        const int4 p = ((const int4*)points)[gs];
        const int p0y = p.x, p0x = p.y, p1y = p.z, p1x = p.w;
        dy0i = abs(p0y - p1y); dx0i = abs(p0x - p1x);
        const float dy0f = (float)dy0i, dx0f = (float)dx0i;
        const float basef = dy0f + dx0f;
        const int idx0 = p0y * GW + p0x;
        const int idx1 = p1y * GW + p1x;
        rs = r[idx0];                          // quad-uniform -> broadcast
        re = r[idx1];
        const float p0yf = (float)p0y, p0xf = (float)p0x;
        const float p1yf = (float)p1y, p1xf = (float)p1x;

#pragma unroll
        for (int i = 0; i < 6; ++i) v4[i] = ((const float4*)r)[4 * i + q];
        v4[6] = make_float4(0.f, 0.f, 0.f, 0.f);
        if (q == 0) v4[6] = ((const float4*)r)[24];   // floats 96..99

        float sum_p = 0.f, scA = 0.f, scB = 0.f, box_p = 0.f;
        uint64_t mlo = 0, mhi = 0;
#pragma unroll
        for (int i = 0; i < 7; ++i) {
            const int kbase = (i < 6) ? 4 * (4 * i + q) : (96 + 4 * q);
            const int y0 = (kbase * 205) >> 11;       // kbase/10
            const int x0 = kbase - 10 * y0;           // always even
            const float y0f = (float)y0, x0f = (float)x0;
            const float sy0 = fabsf(y0f - p0yf) + fabsf(y0f - p1yf);
            const float sy1 = fabsf(y0f + 1.f - p0yf) + fabsf(y0f + 1.f - p1yf);
            const bool wrap = (x0 == 8);
            const float vv[4] = {v4[i].x, v4[i].y, v4[i].z, v4[i].w};
            uint32_t nib = 0;
#pragma unroll
            for (int j = 0; j < 4; ++j) {
                const bool w = wrap && (j >= 2);      // rolls to next row
                const float xf = x0f + (w ? (float)(j - 10) : (float)j);
                const float syj = w ? sy1 : sy0;
                const float v = vv[j];
                const float sx = fabsf(xf - p0xf) + fabsf(xf - p1xf);
                sum_p += v;
                scA = fmaf(syj, v, scA);
                scB = fmaf(sx, v, scB);
                box_p += ((sx == dx0f) & (syj == dy0f)) ? v : 0.f;
                // jnp.round half-to-even: for v in [0,1), round==1 <=> v>0.5
                nib |= (v > 0.5f) ? (1u << j) : 0u;
            }
            const uint64_t n64 = (uint64_t)nib;
            const int shhi = (kbase >= 50) ? (kbase - 50) : 0;
            mlo |= (kbase <= 44) ? (n64 << kbase)
                                 : ((kbase == 48) ? ((n64 & 3ull) << 48) : 0);
            mhi |= (kbase >= 52) ? (n64 << shhi)
                                 : ((kbase == 48) ? (n64 >> 2) : 0);
        }
        sum_p += __shfl_xor(sum_p, 1); sum_p += __shfl_xor(sum_p, 2);
        scA   += __shfl_xor(scA, 1);   scA   += __shfl_xor(scA, 2);
        scB   += __shfl_xor(scB, 1);   scB   += __shfl_xor(scB, 2);
        box_p += __shfl_xor(box_p, 1); box_p += __shfl_xor(box_p, 2);
        mlo |= (uint64_t)__shfl_xor((unsigned long long)mlo, 1);
        mlo |= (uint64_t)__shfl_xor((unsigned long long)mlo, 2);
        mhi |= (uint64_t)__shfl_xor((unsigned long long)mhi, 1);
        mhi |= (uint64_t)__shfl_xor((unsigned long long)mhi, 2);
        sum_all = sum_p; boxSum = box_p;
        sc = fmaf(-basef, sum_p, scA + scB);   // sum v*delta
        if (q == 0) { sMlo[s_local] = mlo; sMhi[s_local] = mhi; }
    }
    __syncthreads();

    // ===== phase B: lanes 0..63 flood one sample each =====
    if (tix < 64) {
        const int fgs = blockIdx.x * 64 + tix;
        if (fgs < B) {
            const int4 p = ((const int4*)points)[fgs];   // coalesced reload
            const int p0y = p.x, p0x = p.y, p1y = p.z, p1x = p.w;
            const int base0 = abs(p0y - p1y) + abs(p0x - p1x);
            const int idx0 = p0y * GW + p0x;
            const uint64_t mlo = sMlo[tix], mhi = sMhi[tix];

            const uint64_t M50 = (1ull << 50) - 1;
            const uint64_t C0  = 0x10040100401ull;    // col-0 bit of 5 rows
            const uint64_t NC0 = M50 & ~C0;
            const uint64_t NC9 = M50 & ~(C0 << 9);
            uint64_t clo = 0, chi = 0;
            if (idx0 < 50) clo = 1ull << idx0; else chi = 1ull << (idx0 - 50);
#pragma unroll 1
            for (int it = 0; it < GH + GW; ++it) {    // cap 20 = reference
                const uint64_t hlo = clo | ((clo << 1) & NC0) | ((clo >> 1) & NC9);
                const uint64_t hhi = chi | ((chi << 1) & NC0) | ((chi >> 1) & NC9);
                uint64_t nlo = (hlo | (hlo << 10) | (hlo >> 10) | ((hhi & 0x3FFull) << 40)) & mlo;
                uint64_t nhi = (hhi | (hhi << 10) | (hhi >> 10) | (hlo >> 40)) & mhi;
                nlo |= clo; nhi |= chi;
                if (nlo == clo && nhi == chi) break;  // fixpoint only
                clo = nlo; chi = nhi;
            }
            const int K = __popcll(clo) + __popcll(chi);

            // argmin over cluster cells of dist-to-end, first-flat-index ties
            int bestd = 1000, bidx = 0;
#pragma unroll
            for (int y = 0; y < GH; ++y) {
                const uint32_t rb = (uint32_t)(((y < 5) ? (clo >> (10 * y))
                                                        : (chi >> (10 * (y - 5)))) & 0x3FFull);
                const uint32_t left  = rb & ((2u << p1x) - 1);
                const uint32_t right = rb >> p1x;
                const int dl = left  ? (p1x - (31 - __builtin_clz(left))) : 1000;
                const int dr = right ? __builtin_ctz(right) : 1000;
                int dx, xx;
                if (dl <= dr) { dx = dl; xx = p1x - dl; }   // tie -> smaller col
                else          { dx = dr; xx = p1x + dr; }
                const int d = abs(y - p1y) + dx;
                if (rb && d < bestd) { bestd = d; bidx = y * GW + xx; }
            }

            const bool better = bestd < base0;
            const int ny = better ? bidx / 10 : p0y;
            const int nx = better ? bidx % 10 : p0x;
            const int gap = min(base0, bestd);

            int by = ny, bx = nx, bg = gap;
            const int oy = p1y - ny, ox = p1x - nx;
            auto upd = [&](bool cond, int cy, int cx) {
                const int d = abs(cy - p1y) + abs(cx - p1x);
                if (cond && (d < bg)) { by = cy; bx = cx; bg = d; }
            };
            upd(ox < 0,                     ny,     nx - 1);
            upd((ox < 0) && (ny != 0),      ny - 1, nx - 1);
            upd((ox < 0) && (ny != GH - 1), ny + 1, nx - 1);
            upd(ox > 0,                     ny,     nx + 1);
            upd((ox > 0) && (ny != 0),      ny - 1, nx + 1);
            upd((ox > 0) && (ny != GH - 1), ny + 1, nx + 1);
            upd(oy < 0,                     ny - 1, nx);
            upd(oy > 0,                     ny + 1, nx);
            const int ncy = min(max(by, 0), GH - 1);
            const int ncx = min(max(bx, 0), GW - 1);
            // scattered 4B load; lines were just fetched by this CU -> L1/L2 hit
            const float rn = result[(size_t)fgs * 100 + ncy * GW + ncx];

            sClo[tix] = clo; sChi[tix] = chi; sK[tix] = K;
            sGapPen[tix] = (float)gap * 300.f * (1.f - rn);
        }
    }
    __syncthreads();

    // ===== phase C: quad S_T (values still in registers) + assembly =====
    float loss = 0.f;
    if (valid) {
        const uint64_t clo = sClo[s_local], chi = sChi[s_local];
        const uint32_t cl32 = (uint32_t)clo;
        float st_p = 0.f;
#pragma unroll
        for (int i = 0; i < 7; ++i) {
            const int kbase = (i < 6) ? 4 * (4 * i + q) : (96 + 4 * q);
            const int y0 = (kbase * 205) >> 11;
            const int x0 = kbase - 10 * y0;
            const int s0 = x0 * 10 + y0;      // transposed bit of cell 0
            const uint64_t tA = (clo >> (s0 & 63)) | (chi << ((50 - s0) & 63));
            const uint64_t tB = chi >> ((s0 - 50) & 63);
            const uint32_t tl = (uint32_t)((s0 < 50) ? tA : tB);
            uint32_t nib = (tl & 1u) | ((tl >> 9) & 2u) |
                           ((tl >> 18) & 4u) | ((tl >> 27) & 8u);
            if (x0 == 8) {   // straddle: cells j=2,3 are (y0+1, 0/1)
                const uint32_t b2 = (cl32 >> (y0 + 1)) & 1u;
                const uint32_t b3 = (cl32 >> (y0 + 11)) & 1u;
                nib = (nib & 3u) | (b2 << 2) | (b3 << 3);
            }
            const float vv[4] = {v4[i].x, v4[i].y, v4[i].z, v4[i].w};
#pragma unroll
            for (int j = 0; j < 4; ++j)
                st_p += (nib & (1u << j)) ? vv[j] : 0.f;
        }
        st_p += __shfl_xor(st_p, 1); st_p += __shfl_xor(st_p, 2);

        if (q == 0) {
            const float csf = (float)sK[s_local];
            const float nboxf = (float)((dy0i + 1) * (dx0i + 1));
            const float loss_start = (2.f - (rs + re)) * 1000.f;
            const float lon = 5.f * csf + 15.f * sum_all - 20.f * st_p;
            const float single_cell = 0.5f * sc + 20.f * (nboxf - boxSum);
            const float cpen = 12.f * csf * st_p;
            loss = loss_start + lon + single_cell + cpen + sGapPen[s_local];
        }
    }

    // ---- block reduction: wave shuffle -> LDS -> one atomic per block ----
#pragma unroll
    for (int off = 32; off > 0; off >>= 1)
        loss += __shfl_down(loss, off);
    const int lane = threadIdx.x & 63;
    const int wid = threadIdx.x >> 6;
    if (lane == 0) wsum[wid] = loss;
    __syncthreads();
    if (threadIdx.x == 0)
        atomicAdd(out, wsum[0] + wsum[1] + wsum[2] + wsum[3]);
}

extern "C" void kernel_launch(void* const* d_in, const int* in_sizes, int n_in,
                              void* d_out, int out_size, void* d_ws, size_t ws_size,
                              hipStream_t stream)
{
    const float* result = (const float*)d_in[0];
    const int* points   = (const int*)d_in[1];
    float* out = (float*)d_out;
    const int B = in_sizes[0] / 100;
    hipMemsetAsync(out, 0, sizeof(float), stream);   // harness poisons d_out with 0xAA
    const int block = 256;                            // 64 samples per block
    const int grid = (B + 63) / 64;
    custom_loss_kernel<<<grid, block, 0, stream>>>(result, points, out, B);
}